// Round 2
// baseline (108.478 us; speedup 1.0000x reference)
//
#include <hip/hip_runtime.h>
#include <math.h>

// TwistorResonance: B=2, N=4096 (hardcoded N; B derived from in_sizes).
// R_ij = |z_i||z_j| * |cos((phi_i-phi_j)*sens)|^expo, top-(8N+1) threshold over
// flattened N^2, keep R>=thr, out = alpha * [R@zr, R@zi] stacked last-dim.
//
// Round-12: persistent kernel with HAND-ROLLED device barrier (2 dispatches).
//   Round-11 post-mortem: hipLaunchCooperativeKernel is not graph-capturable
//   (timed path silently ran the 7-kernel fallback at ~108us), and ROCm's
//   grid.sync costs ~150us/sync at 832 blocks (rocprof: 953us, VALUBusy 2%).
//   Fix: plain launch (capturable) + minimal agent-scope barrier: release
//   fence -> one atomicAdd/block on an LLC counter -> poll generation word
//   (relaxed agent loads + s_sleep) -> acquire fence. ~2-5us/sync expected.
//   Dispatches: hipMemsetAsync(~200KB hist+bar region) + tw_persist(P0..P6).
//   Co-residency: 832 blocks, 36.9KB LDS -> 4 blk/CU, lb(256,4); host-side
//   occupancy gate falls back to the PROVEN round-10 7-kernel path.
//   Phase math byte-identical to round-10 (absmax 0.0).
//
// Phases inside tw_persist (tw_gbar between each):
//  P0 init      : jfast(v,phi) + jexact + zero out. (hists zeroed by memset)
//  P1 histW     : 4-way lane-replicated 2048-bin LDS hist of w float-bits.
//  P2 collectW  : inline wmin scan (guard 2 bins) -> private per-block segs.
//  P3 gexact    : inline offset sum + gather + exact libm + phase0 hist (hA).
//  P4 chist1    : inline scanA -> binA; filtered phase-1 hist (hB).
//  P5 chist2    : inline scanA+scanB -> filtered phase-2 hist (hC).
//  P6 scatter   : inline scanA+scanB+scanC -> exact thr; atomicAdd outputs.

#define TW_N 4096
#define TW_TILE 64
#define TW_NBLK (TW_N / TW_TILE)                 // 64
#define TW_TRI (TW_NBLK * (TW_NBLK + 1) / 2)     // 2080
#define TW_TPB 5                                 // tri-tiles per block
#define TW_TBLK (TW_TRI / TW_TPB)                // 416 blocks per batch
#define TW_SEGCAP (TW_TPB * TW_TILE * TW_TILE)   // 20480: structural max
#define TW_NPART 8                               // partial global hists
#define TW_CAND_CAP (1 << 19)
#define TW_CBLK 64
#define TW_SBLK 128

__device__ __forceinline__ float tw_softplus(float x) {
    return fmaxf(x, 0.0f) + log1pf(expf(-fabsf(x)));
}

__device__ __forceinline__ float tw_expo(const float* ksp, const float* kbp) {
    return tw_softplus(*ksp) + tw_softplus(*kbp) + 1e-6f;
}

// exact path (libm) — bit-identical to rounds 1-10 (absmax 0.0 vs numpy)
__device__ __forceinline__ float tw_R(float amp_i, float phi_i,
                                      float amp_j, float phi_j,
                                      float sens, float expo) {
    float dphi = phi_i - phi_j;
    float c = fabsf(cosf(dphi * sens));
    c = fmaxf(c, 1e-10f);
    float ph = powf(c, expo);
    return amp_i * amp_j * ph;
}

// triangular tile decode: tiles (bi,bj), bi<=bj, row-major in bi.
__device__ __forceinline__ int tw_rowstart(int bi) {
    return bi * TW_NBLK - ((bi * (bi - 1)) >> 1);
}
__device__ __forceinline__ void tw_decode(int tt, int& bi, int& bj) {
    const float A = (float)(2 * TW_NBLK + 1);
    float disc = A * A - 8.0f * (float)tt;
    int b = (int)((A - sqrtf(disc)) * 0.5f);
    if (b < 0) b = 0;
    if (b > TW_NBLK - 1) b = TW_NBLK - 1;
    while (b + 1 <= TW_NBLK - 1 && tw_rowstart(b + 1) <= tt) ++b;
    while (b > 0 && tw_rowstart(b) > tt) --b;
    bi = b;
    bj = b + (tt - tw_rowstart(b));
}

// ---- minimal device-wide barrier (all blocks co-resident, plain launch) ----
// bar[0]: monotonic arrival counter; bar[1]: generation. Both zeroed by the
// preceding hipMemsetAsync. Release fence makes this block's regular stores
// LLC-visible (wbl2); acquire fence invalidates stale L1/L2 lines.
__device__ __forceinline__ void tw_gbar(unsigned* bar, unsigned target, unsigned gen) {
    __syncthreads();
    __builtin_amdgcn_fence(__ATOMIC_RELEASE, "agent");
    if (threadIdx.x == 0) {
        unsigned v = __hip_atomic_fetch_add(&bar[0], 1u, __ATOMIC_RELAXED,
                                            __HIP_MEMORY_SCOPE_AGENT);
        if (v + 1u == target) {
            __hip_atomic_store(&bar[1], gen, __ATOMIC_RELAXED,
                               __HIP_MEMORY_SCOPE_AGENT);
        } else {
            while (__hip_atomic_load(&bar[1], __ATOMIC_RELAXED,
                                     __HIP_MEMORY_SCOPE_AGENT) < gen)
                __builtin_amdgcn_s_sleep(2);
        }
    }
    __syncthreads();
    __builtin_amdgcn_fence(__ATOMIC_ACQUIRE, "agent");
}

// block-cooperative top-down radix scan over NB-bin hist; all 256 threads.
template <int NB>
__device__ void tw_scan_dev(const unsigned* __restrict__ h, unsigned Kp_in,
                            unsigned& bin_out, unsigned& kp_out) {
    __shared__ unsigned ps_[256];
    __shared__ unsigned shb_, shk_;
    constexpr int CHUNK = NB / 256;
    const int t = threadIdx.x;
    __syncthreads();                         // protect static-shared reuse
    unsigned s = 0;
    for (int k = 0; k < CHUNK; ++k) s += h[NB - 1 - (t * CHUNK + k)];
    ps_[t] = s;
    __syncthreads();
    for (int off = 1; off < 256; off <<= 1) {
        unsigned v = (t >= off) ? ps_[t - off] : 0u;
        __syncthreads();
        ps_[t] += v;
        __syncthreads();
    }
    unsigned excl = (t == 0) ? 0u : ps_[t - 1];
    if (excl < Kp_in && Kp_in <= ps_[t]) {
        unsigned run = excl;
        for (int k = 0; k < CHUNK; ++k) {
            int bin = NB - 1 - (t * CHUNK + k);
            unsigned c = h[bin];
            if (run + c >= Kp_in) { shb_ = (unsigned)bin; shk_ = Kp_in - run; break; }
            run += c;
        }
    }
    __syncthreads();
    bin_out = shb_; kp_out = shk_;
}

// block-cooperative wmin from 8 partial 2048-bin hists (guard 2 bins).
__device__ float tw_wmin_dev(const unsigned* __restrict__ histp, int b, int B, unsigned K) {
    __shared__ unsigned ps_[256];
    __shared__ unsigned shm_;
    const int t = threadIdx.x;
    unsigned s = 0;
    for (int k = 0; k < 8; ++k) {
        int bin = 2047 - (t * 8 + k);
        for (int p = 0; p < TW_NPART; ++p)
            s += histp[((size_t)p * B + b) * 2048 + bin];
    }
    ps_[t] = s;
    __syncthreads();
    for (int off = 1; off < 256; off <<= 1) {
        unsigned v = (t >= off) ? ps_[t - off] : 0u;
        __syncthreads();
        ps_[t] += v;
        __syncthreads();
    }
    unsigned excl = (t == 0) ? 0u : ps_[t - 1];
    if (excl < K && K <= ps_[t]) {
        unsigned run = excl;
        for (int k = 0; k < 8; ++k) {
            int bin = 2047 - (t * 8 + k);
            unsigned c = 0;
            for (int p = 0; p < TW_NPART; ++p)
                c += histp[((size_t)p * B + b) * 2048 + bin];
            if (run + c >= K) {
                int mb = bin - 2; if (mb < 0) mb = 0;
                shm_ = (unsigned)mb << 20;
                break;
            }
            run += c;
        }
    }
    __syncthreads();
    return __uint_as_float(shm_);
}

// candidate weight: off-diagonal TILE pairs represent (i,j) and (j,i) -> 2
__device__ __forceinline__ unsigned tw_w(unsigned pij) {
    return ((pij >> 18) == ((pij >> 6) & 63u)) ? 1u : 2u;
}

// ================= Round-12 persistent kernel (plain launch) =================
// LDS: s_lh 32KB (reused per phase) + tiles 516B + scan statics ~2KB => 36.9KB
// -> 4 blocks/CU; grid 416*B=832 <= 1024 co-resident (checked host-side).
__global__ void __launch_bounds__(256, 4)
tw_persist(const float* zr, const float* zi,
           const float* alphap, const float* ksp, const float* kbp, const float* sensp,
           float* out, int out_words,
           unsigned* hP, unsigned* hA, unsigned* hB, unsigned* hC,
           unsigned* cnt, unsigned* ccount,
           float2* jfast, float4* jexact,
           unsigned* cidx, float* cval, unsigned* seg,
           unsigned* bar, int N, int B, int total, unsigned K) {
    __shared__ unsigned s_lh[2048 * 4];
    __shared__ float s_jv[TW_TILE], s_jp[TW_TILE];
    __shared__ unsigned s_cn;

    const int tid = threadIdx.x;
    const int b = blockIdx.y;
    const int bx = blockIdx.x;
    const unsigned nbar = gridDim.x * gridDim.y;

    // ---- P0: jfast/jexact + zero out (hists+bar zeroed by memset) ----
    {
        const int bid = blockIdx.y * gridDim.x + blockIdx.x;
        const int idx0 = bid * 256 + tid;
        const int stride = (int)nbar * 256;
        for (int k = idx0; k < out_words; k += stride) out[k] = 0.0f;
        const float e = tw_expo(ksp, kbp);
        for (int k = idx0; k < total; k += stride) {
            float r = zr[k], m = zi[k];
            float amp = sqrtf(r * r + m * m);
            float phi = atan2f(m, r);
            jexact[k] = make_float4(amp, phi, r, m);
            jfast[k] = make_float2(powf(amp, 1.0f / e), phi);   // v = amp^(1/e)
        }
    }
    tw_gbar(bar, nbar * 1u, 1u);

    // ---- P1: 4-way lane-replicated 2048-bin hist of w float-bits ----
    {
        for (int k = tid; k < 2048 * 4; k += 256) s_lh[k] = 0u;
        const float sens = *sensp;
        const int jj = tid & 63, r0 = tid >> 6, rep = tid & 3;
        int bi, bj;
        tw_decode(bx * TW_TPB, bi, bj);
        for (int s = 0; s < TW_TPB; ++s) {
            __syncthreads();
            if (tid < TW_TILE) {
                float2 w = jfast[b * N + bj * TW_TILE + tid];
                s_jv[tid] = w.x; s_jp[tid] = w.y;
            }
            float vi[16], ph[16];
#pragma unroll
            for (int k = 0; k < 16; ++k) {
                float2 v = jfast[b * N + bi * TW_TILE + r0 + (k << 2)];  // wave-uniform
                vi[k] = v.x; ph[k] = v.y;
            }
            __syncthreads();
            const float vj = s_jv[jj], pj = s_jp[jj];
            const unsigned inc = (bi == bj) ? 1u : 2u;
#pragma unroll
            for (int k = 0; k < 16; ++k) {
                float w = vi[k] * vj * fabsf(__cosf((ph[k] - pj) * sens));
                atomicAdd(&s_lh[((__float_as_uint(w) >> 20) << 2) + rep], inc);
            }
            ++bj;
            if (bj >= TW_NBLK) { ++bi; bj = bi; }
        }
        __syncthreads();
        unsigned* hp = hP + ((size_t)(bx & (TW_NPART - 1)) * B + b) * 2048;
        const int rot = (int)((bx * 191u + b * 977u) & 2047u);
        for (int kk = tid; kk < 2048; kk += 256) {
            int k = (kk + rot) & 2047;
            unsigned v = s_lh[k * 4] + s_lh[k * 4 + 1] + s_lh[k * 4 + 2] + s_lh[k * 4 + 3];
            if (v) atomicAdd(&hp[k], v);
        }
    }
    tw_gbar(bar, nbar * 2u, 2u);

    // ---- P2: collect (inline wmin): w >= wmin -> private per-block segment ----
    {
        const float wmin = tw_wmin_dev(hP, b, B, K);
        if (tid == 0) s_cn = 0u;
        const float sens = *sensp;
        const int jj = tid & 63, r0 = tid >> 6;
        const int gid = b * TW_TBLK + bx;
        unsigned* sg = seg + (size_t)gid * TW_SEGCAP;
        int bi, bj;
        tw_decode(bx * TW_TPB, bi, bj);
        for (int s = 0; s < TW_TPB; ++s) {
            __syncthreads();
            if (tid < TW_TILE) {
                float2 w = jfast[b * N + bj * TW_TILE + tid];
                s_jv[tid] = w.x; s_jp[tid] = w.y;
            }
            float vi[16], ph[16];
#pragma unroll
            for (int k = 0; k < 16; ++k) {
                float2 v = jfast[b * N + bi * TW_TILE + r0 + (k << 2)];
                vi[k] = v.x; ph[k] = v.y;
            }
            __syncthreads();
            const float vj = s_jv[jj], pj = s_jp[jj];
            const unsigned ib = (unsigned)(bi * TW_TILE);
            const unsigned jg = (unsigned)(bj * TW_TILE) + (unsigned)jj;
#pragma unroll
            for (int k = 0; k < 16; ++k) {
                float w = vi[k] * vj * fabsf(__cosf((ph[k] - pj) * sens));
                if (w >= wmin) {
                    unsigned p = atomicAdd(&s_cn, 1u);   // LDS ticket, block-local
                    sg[p] = ((ib + (unsigned)(r0 + (k << 2))) << 12) | jg;
                }
            }
            ++bj;
            if (bj >= TW_NBLK) { ++bi; bj = bi; }
        }
        __syncthreads();
        if (tid == 0) cnt[gid] = s_cn;
    }
    tw_gbar(bar, nbar * 3u, 3u);

    // ---- P3: inline-offset + gather + exact libm + radix phase0 hist (hA) ----
    {
        unsigned* lh = s_lh;              // 4096 words
        unsigned* red = s_lh + 4096;      // 256 words
        for (int k = tid; k < 4096; k += 256) lh[k] = 0u;
        unsigned partial = 0;
        for (int k = tid; k < bx; k += 256) partial += cnt[b * TW_TBLK + k];
        red[tid] = partial;
        __syncthreads();
        for (int off = 128; off; off >>= 1) {
            if (tid < off) red[tid] += red[tid + off];
            __syncthreads();
        }
        const unsigned dbase = red[0];
        const int gid = b * TW_TBLK + bx;
        const unsigned n = cnt[gid];
        if (bx == TW_TBLK - 1 && tid == 0) ccount[b] = dbase + n;
        const unsigned* src = seg + (size_t)gid * TW_SEGCAP;
        const float sens = *sensp;
        const float expo = tw_expo(ksp, kbp);
        __syncthreads();
        for (unsigned k = tid; k < n; k += 256) {
            unsigned pij = src[k];
            unsigned d = dbase + k;
            if (d >= (unsigned)TW_CAND_CAP) continue;
            const unsigned i = pij >> 12, j = pij & 4095u;
            float4 di = jexact[b * N + i];
            float4 dj = jexact[b * N + j];
            float val = tw_R(di.x, di.y, dj.x, dj.y, sens, expo);
            cidx[(size_t)b * TW_CAND_CAP + d] = pij;
            cval[(size_t)b * TW_CAND_CAP + d] = val;
            atomicAdd(&lh[__float_as_uint(val) >> 20], tw_w(pij));
        }
        __syncthreads();
        for (int k = tid; k < 4096; k += 256) {
            unsigned v = lh[k];
            if (v) atomicAdd(&hA[b * 4096 + k], v);
        }
    }
    tw_gbar(bar, nbar * 4u, 4u);

    // ---- P4: chist phase1 with inline scanA ----
    {
        unsigned binA, KpA;
        tw_scan_dev<4096>(hA + (size_t)b * 4096, K, binA, KpA);
        for (int k = tid; k < 4096; k += 256) s_lh[k] = 0u;
        unsigned nb = ccount[b]; if (nb > (unsigned)TW_CAND_CAP) nb = (unsigned)TW_CAND_CAP;
        const float* cv = cval + (size_t)b * TW_CAND_CAP;
        const unsigned* ci = cidx + (size_t)b * TW_CAND_CAP;
        __syncthreads();
        const unsigned stride = gridDim.x * 256;
        for (unsigned idx = bx * 256 + tid; idx < nb; idx += stride) {
            unsigned bits = __float_as_uint(cv[idx]);
            if ((bits >> 20) == binA) atomicAdd(&s_lh[(bits >> 8) & 0xFFFu], tw_w(ci[idx]));
        }
        __syncthreads();
        for (int k = tid; k < 4096; k += 256) {
            unsigned v = s_lh[k];
            if (v) atomicAdd(&hB[b * 4096 + k], v);
        }
    }
    tw_gbar(bar, nbar * 5u, 5u);

    // ---- P5: chist phase2 with inline scanA+scanB ----
    {
        unsigned binA, KpA, binB, KpB;
        tw_scan_dev<4096>(hA + (size_t)b * 4096, K, binA, KpA);
        tw_scan_dev<4096>(hB + (size_t)b * 4096, KpA, binB, KpB);
        if (tid < 256) s_lh[tid] = 0u;
        unsigned nb = ccount[b]; if (nb > (unsigned)TW_CAND_CAP) nb = (unsigned)TW_CAND_CAP;
        const unsigned pf24 = (binA << 12) | binB;
        const float* cv = cval + (size_t)b * TW_CAND_CAP;
        const unsigned* ci = cidx + (size_t)b * TW_CAND_CAP;
        __syncthreads();
        const unsigned stride = gridDim.x * 256;
        for (unsigned idx = bx * 256 + tid; idx < nb; idx += stride) {
            unsigned bits = __float_as_uint(cv[idx]);
            if ((bits >> 8) == pf24) atomicAdd(&s_lh[bits & 0xFFu], tw_w(ci[idx]));
        }
        __syncthreads();
        if (tid < 256) {
            unsigned v = s_lh[tid];
            if (v) atomicAdd(&hC[b * 256 + tid], v);
        }
    }
    tw_gbar(bar, nbar * 6u, 6u);

    // ---- P6: scatter with inline scanA+scanB+scanC -> exact thr ----
    {
        unsigned binA, KpA, binB, KpB, binC, KpC;
        tw_scan_dev<4096>(hA + (size_t)b * 4096, K, binA, KpA);
        tw_scan_dev<4096>(hB + (size_t)b * 4096, KpA, binB, KpB);
        tw_scan_dev<256>(hC + (size_t)b * 256, KpB, binC, KpC);
        const float T = __uint_as_float((binA << 20) | (binB << 8) | binC);
        unsigned nb = ccount[b]; if (nb > (unsigned)TW_CAND_CAP) nb = (unsigned)TW_CAND_CAP;
        const float alpha = *alphap;
        const unsigned stride = gridDim.x * 256;
        for (unsigned idx = bx * 256 + tid; idx < nb; idx += stride) {
            const float v = cval[(size_t)b * TW_CAND_CAP + idx];
            if (v < T) continue;
            const unsigned pij = cidx[(size_t)b * TW_CAND_CAP + idx];
            const unsigned i = pij >> 12, j = pij & 4095u;
            float4 dj = jexact[b * N + j];
            atomicAdd(&out[(size_t)(b * N + i) * 2 + 0], alpha * v * dj.z);
            atomicAdd(&out[(size_t)(b * N + i) * 2 + 1], alpha * v * dj.w);
            if ((pij >> 18) != ((pij >> 6) & 63u)) {   // off-diagonal tile -> mirror
                float4 di = jexact[b * N + i];
                atomicAdd(&out[(size_t)(b * N + j) * 2 + 0], alpha * v * di.z);
                atomicAdd(&out[(size_t)(b * N + j) * 2 + 1], alpha * v * di.w);
            }
        }
    }
}

// ================= Round-10 7-kernel path (fallback) =================

// ---- 0. init ----
__global__ void tw_init(const float* __restrict__ zr, const float* __restrict__ zi,
                        float2* __restrict__ jfast, float4* __restrict__ jexact,
                        unsigned* __restrict__ zero_base, int zero_words,
                        float* __restrict__ out, int out_words,
                        const float* ksp, const float* kbp, int total) {
    const int idx = blockIdx.x * blockDim.x + threadIdx.x;
    const int stride = gridDim.x * blockDim.x;
    for (int k = idx; k < zero_words; k += stride) zero_base[k] = 0u;
    for (int k = idx; k < out_words; k += stride) out[k] = 0.0f;
    if (idx < total) {
        float r = zr[idx], m = zi[idx];
        float amp = sqrtf(r * r + m * m);
        float phi = atan2f(m, r);
        jexact[idx] = make_float4(amp, phi, r, m);
        float e = tw_expo(ksp, kbp);
        jfast[idx] = make_float2(powf(amp, 1.0f / e), phi);   // v = amp^(1/e)
    }
}

// ---- 1. 4-way lane-replicated 2048-bin hist of w float-bits ----
__global__ void tw_histW(const float2* __restrict__ jf, unsigned* __restrict__ histp,
                         const float* __restrict__ sensp, int N, int B) {
    __shared__ float s_jv[TW_TILE], s_jp[TW_TILE];
    __shared__ unsigned lh[2048 * 4];            // lh[bin*4 + rep]: distinct banks
    const int b = blockIdx.y, tid = threadIdx.x;
    const int jj = tid & 63, r0 = tid >> 6;
    const int rep = tid & 3;
    for (int k = tid; k < 2048 * 4; k += 256) lh[k] = 0u;
    const float sens = *sensp;
    int bi, bj;
    tw_decode(blockIdx.x * TW_TPB, bi, bj);
    for (int s = 0; s < TW_TPB; ++s) {
        __syncthreads();
        if (tid < TW_TILE) {
            float2 w = jf[b * N + bj * TW_TILE + tid];
            s_jv[tid] = w.x; s_jp[tid] = w.y;
        }
        float vi[16], ph[16];
#pragma unroll
        for (int k = 0; k < 16; ++k) {
            float2 v = jf[b * N + bi * TW_TILE + r0 + (k << 2)];  // wave-uniform
            vi[k] = v.x; ph[k] = v.y;
        }
        __syncthreads();
        const float vj = s_jv[jj], pj = s_jp[jj];
        const unsigned inc = (bi == bj) ? 1u : 2u;
#pragma unroll
        for (int k = 0; k < 16; ++k) {
            float w = vi[k] * vj * fabsf(__cosf((ph[k] - pj) * sens));
            atomicAdd(&lh[((__float_as_uint(w) >> 20) << 2) + rep], inc);
        }
        ++bj;
        if (bj >= TW_NBLK) { ++bi; bj = bi; }
    }
    __syncthreads();
    unsigned* hp = histp + ((size_t)(blockIdx.x & (TW_NPART - 1)) * B + b) * 2048;
    const int rot = (int)((blockIdx.x * 191u + b * 977u) & 2047u);
    for (int kk = tid; kk < 2048; kk += 256) {
        int k = (kk + rot) & 2047;
        unsigned v = lh[k * 4] + lh[k * 4 + 1] + lh[k * 4 + 2] + lh[k * 4 + 3];
        if (v) atomicAdd(&hp[k], v);
    }
}

// ---- 2. collect (inline wmin): w >= wmin -> private per-block segment ----
__global__ void tw_collectW(const float2* __restrict__ jf, const unsigned* __restrict__ histp,
                            unsigned* __restrict__ seg, unsigned* __restrict__ cnt,
                            const float* __restrict__ sensp, int N, int B, unsigned K) {
    __shared__ float s_jv[TW_TILE], s_jp[TW_TILE];
    __shared__ unsigned cn;
    const int b = blockIdx.y, tid = threadIdx.x;
    const int jj = tid & 63, r0 = tid >> 6;
    const float wmin = tw_wmin_dev(histp, b, B, K);
    if (tid == 0) cn = 0u;
    const float sens = *sensp;
    const int gid = b * TW_TBLK + blockIdx.x;
    unsigned* sg = seg + (size_t)gid * TW_SEGCAP;
    int bi, bj;
    tw_decode(blockIdx.x * TW_TPB, bi, bj);
    for (int s = 0; s < TW_TPB; ++s) {
        __syncthreads();
        if (tid < TW_TILE) {
            float2 w = jf[b * N + bj * TW_TILE + tid];
            s_jv[tid] = w.x; s_jp[tid] = w.y;
        }
        float vi[16], ph[16];
#pragma unroll
        for (int k = 0; k < 16; ++k) {
            float2 v = jf[b * N + bi * TW_TILE + r0 + (k << 2)];
            vi[k] = v.x; ph[k] = v.y;
        }
        __syncthreads();
        const float vj = s_jv[jj], pj = s_jp[jj];
        const unsigned ib = (unsigned)(bi * TW_TILE);
        const unsigned jg = (unsigned)(bj * TW_TILE) + (unsigned)jj;
#pragma unroll
        for (int k = 0; k < 16; ++k) {
            float w = vi[k] * vj * fabsf(__cosf((ph[k] - pj) * sens));
            if (w >= wmin) {
                unsigned p = atomicAdd(&cn, 1u);   // LDS ticket, block-local
                sg[p] = ((ib + (unsigned)(r0 + (k << 2))) << 12) | jg;
            }
        }
        ++bj;
        if (bj >= TW_NBLK) { ++bi; bj = bi; }
    }
    __syncthreads();
    if (tid == 0) cnt[gid] = cn;
}

// ---- 3. FUSED inline-offset + gather + exact libm + radix phase0 hist ----
__global__ void tw_gexact(const unsigned* __restrict__ seg, const unsigned* __restrict__ cnt,
                          unsigned* __restrict__ cand_idx, float* __restrict__ cand_val,
                          const float4* __restrict__ jdata, unsigned* __restrict__ histA,
                          unsigned* __restrict__ ccount,
                          const float* ksp, const float* kbp, const float* sensp,
                          int N, int perb, int cap) {
    __shared__ unsigned lh[4096];
    __shared__ unsigned red[256];
    const int b = blockIdx.y, tid = threadIdx.x;
    for (int k = tid; k < 4096; k += 256) lh[k] = 0u;
    // exclusive offset of this block within batch b (replaces cscan)
    unsigned partial = 0;
    for (int k = tid; k < (int)blockIdx.x; k += 256) partial += cnt[b * perb + k];
    red[tid] = partial;
    __syncthreads();
    for (int off = 128; off; off >>= 1) {
        if (tid < off) red[tid] += red[tid + off];
        __syncthreads();
    }
    const unsigned dbase = red[0];
    const int gid = b * perb + blockIdx.x;
    const unsigned n = cnt[gid];
    if (blockIdx.x == perb - 1 && tid == 0) ccount[b] = dbase + n;
    const unsigned* src = seg + (size_t)gid * TW_SEGCAP;
    const float sens = *sensp;
    const float expo = tw_expo(ksp, kbp);
    __syncthreads();
    for (unsigned k = tid; k < n; k += 256) {
        unsigned pij = src[k];
        unsigned d = dbase + k;
        if (d >= (unsigned)cap) continue;
        const unsigned i = pij >> 12, j = pij & 4095u;
        float4 di = jdata[b * N + i];
        float4 dj = jdata[b * N + j];
        float val = tw_R(di.x, di.y, dj.x, dj.y, sens, expo);
        cand_idx[(size_t)b * cap + d] = pij;
        cand_val[(size_t)b * cap + d] = val;
        atomicAdd(&lh[__float_as_uint(val) >> 20], tw_w(pij));
    }
    __syncthreads();
    for (int k = tid; k < 4096; k += 256) {
        unsigned v = lh[k];
        if (v) atomicAdd(&histA[b * 4096 + k], v);
    }
}

// ---- 4. chist phase1 with inline scanA ----
__global__ void tw_chist1f(const float* __restrict__ cand_val, const unsigned* __restrict__ cand_idx,
                           const unsigned* __restrict__ ccount, const unsigned* __restrict__ histA,
                           unsigned* __restrict__ histB, unsigned K, int cap) {
    __shared__ unsigned lh[4096];
    const int b = blockIdx.y, tid = threadIdx.x;
    unsigned binA, KpA;
    tw_scan_dev<4096>(histA + (size_t)b * 4096, K, binA, KpA);
    for (int k = tid; k < 4096; k += 256) lh[k] = 0u;
    unsigned nb = ccount[b]; if (nb > (unsigned)cap) nb = (unsigned)cap;
    const float* cv = cand_val + (size_t)b * cap;
    const unsigned* ci = cand_idx + (size_t)b * cap;
    __syncthreads();
    const unsigned stride = gridDim.x * 256;
    for (unsigned idx = blockIdx.x * 256 + tid; idx < nb; idx += stride) {
        unsigned bits = __float_as_uint(cv[idx]);
        if ((bits >> 20) == binA) atomicAdd(&lh[(bits >> 8) & 0xFFFu], tw_w(ci[idx]));
    }
    __syncthreads();
    for (int k = tid; k < 4096; k += 256) {
        unsigned v = lh[k];
        if (v) atomicAdd(&histB[b * 4096 + k], v);
    }
}

// ---- 5. chist phase2 with inline scanA+scanB ----
__global__ void tw_chist2f(const float* __restrict__ cand_val, const unsigned* __restrict__ cand_idx,
                           const unsigned* __restrict__ ccount, const unsigned* __restrict__ histA,
                           const unsigned* __restrict__ histB, unsigned* __restrict__ histC,
                           unsigned K, int cap) {
    __shared__ unsigned lh[256];
    const int b = blockIdx.y, tid = threadIdx.x;
    unsigned binA, KpA, binB, KpB;
    tw_scan_dev<4096>(histA + (size_t)b * 4096, K, binA, KpA);
    tw_scan_dev<4096>(histB + (size_t)b * 4096, KpA, binB, KpB);
    if (tid < 256) lh[tid] = 0u;
    unsigned nb = ccount[b]; if (nb > (unsigned)cap) nb = (unsigned)cap;
    const unsigned pf24 = (binA << 12) | binB;
    const float* cv = cand_val + (size_t)b * cap;
    const unsigned* ci = cand_idx + (size_t)b * cap;
    __syncthreads();
    const unsigned stride = gridDim.x * 256;
    for (unsigned idx = blockIdx.x * 256 + tid; idx < nb; idx += stride) {
        unsigned bits = __float_as_uint(cv[idx]);
        if ((bits >> 8) == pf24) atomicAdd(&lh[bits & 0xFFu], tw_w(ci[idx]));
    }
    __syncthreads();
    if (tid < 256) {
        unsigned v = lh[tid];
        if (v) atomicAdd(&histC[b * 256 + tid], v);
    }
}

// ---- 6. scatter with inline scanA+scanB+scanC -> exact thr ----
__global__ void tw_scatterf(const float* __restrict__ cand_val, const unsigned* __restrict__ cand_idx,
                            const unsigned* __restrict__ ccount, const unsigned* __restrict__ histA,
                            const unsigned* __restrict__ histB, const unsigned* __restrict__ histC,
                            const float4* __restrict__ jdata, const float* alphap,
                            float* __restrict__ out, unsigned K, int N, int cap) {
    const int b = blockIdx.y;
    unsigned binA, KpA, binB, KpB, binC, KpC;
    tw_scan_dev<4096>(histA + (size_t)b * 4096, K, binA, KpA);
    tw_scan_dev<4096>(histB + (size_t)b * 4096, KpA, binB, KpB);
    tw_scan_dev<256>(histC + (size_t)b * 256, KpB, binC, KpC);
    const float T = __uint_as_float((binA << 20) | (binB << 8) | binC);
    unsigned nb = ccount[b]; if (nb > (unsigned)cap) nb = (unsigned)cap;
    const float alpha = *alphap;
    const unsigned stride = gridDim.x * 256;
    for (unsigned idx = blockIdx.x * 256 + threadIdx.x; idx < nb; idx += stride) {
        const float v = cand_val[(size_t)b * cap + idx];
        if (v < T) continue;
        const unsigned pij = cand_idx[(size_t)b * cap + idx];
        const unsigned i = pij >> 12, j = pij & 4095u;
        float4 dj = jdata[b * N + j];
        atomicAdd(&out[(size_t)(b * N + i) * 2 + 0], alpha * v * dj.z);
        atomicAdd(&out[(size_t)(b * N + i) * 2 + 1], alpha * v * dj.w);
        if ((pij >> 18) != ((pij >> 6) & 63u)) {   // off-diagonal tile -> mirror
            float4 di = jdata[b * N + i];
            atomicAdd(&out[(size_t)(b * N + j) * 2 + 0], alpha * v * di.z);
            atomicAdd(&out[(size_t)(b * N + j) * 2 + 1], alpha * v * di.w);
        }
    }
}

// ---------------- legacy fallback (round-1 pipeline) ----------------

__global__ void tw_precompute(const float* __restrict__ zr, const float* __restrict__ zi,
                              float4* __restrict__ jdata, unsigned* __restrict__ state,
                              int total, int B, unsigned K) {
    int idx = blockIdx.x * blockDim.x + threadIdx.x;
    if (idx < total) {
        float r = zr[idx], m = zi[idx];
        float amp = sqrtf(r * r + m * m);
        float phi = atan2f(m, r);
        jdata[idx] = make_float4(amp, phi, r, m);
    }
    if (idx < B) { state[idx * 2 + 0] = 0u; state[idx * 2 + 1] = K; }
}

template <int PASS>
__global__ void tw_hist(const float4* __restrict__ jdata, unsigned* __restrict__ hist,
                        const unsigned* __restrict__ state,
                        const float* ksp, const float* kbp, const float* sensp, int N) {
    constexpr int NB = (PASS == 3) ? 256 : 4096;
    __shared__ float sa[256], sphi[256];
    __shared__ unsigned lh[NB];
    const int b = blockIdx.z;
    const int i = blockIdx.x * 256 + threadIdx.x;
    const int j0 = blockIdx.y * 256;

    for (int k = threadIdx.x; k < NB; k += 256) lh[k] = 0u;

    float4 mine = jdata[b * N + i];
    float amp_i = mine.x, phi_i = mine.y;
    float4 jd = jdata[b * N + j0 + threadIdx.x];
    sa[threadIdx.x] = jd.x; sphi[threadIdx.x] = jd.y;

    const float sens = *sensp;
    const float expo = tw_expo(ksp, kbp);
    unsigned pf = 0;
    if (PASS > 1) pf = state[b * 2 + 0];
    __syncthreads();

    for (int j = 0; j < 256; ++j) {
        float R = tw_R(amp_i, phi_i, sa[j], sphi[j], sens, expo);
        unsigned bits = __float_as_uint(R);
        if (PASS == 1) {
            atomicAdd(&lh[bits >> 20], 1u);
        } else if (PASS == 2) {
            if ((bits >> 20) == (pf >> 20)) atomicAdd(&lh[(bits >> 8) & 0xFFFu], 1u);
        } else {
            if ((bits >> 8) == (pf >> 8)) atomicAdd(&lh[bits & 0xFFu], 1u);
        }
    }
    __syncthreads();
    for (int k = threadIdx.x; k < NB; k += 256) {
        unsigned v = lh[k];
        if (v) atomicAdd(&hist[b * NB + k], v);
    }
}

template <int NB, int SHIFT>
__global__ void tw_scan(const unsigned* __restrict__ hist, unsigned* __restrict__ state,
                        float* __restrict__ thr, int B) {
    __shared__ unsigned ps[256];
    constexpr int CHUNK = NB / 256;
    const int t = threadIdx.x;
    for (int b = 0; b < B; ++b) {
        const unsigned* h = hist + b * NB;
        unsigned prefix = state[b * 2 + 0];
        unsigned Kp     = state[b * 2 + 1];
        unsigned s = 0;
        for (int k = 0; k < CHUNK; ++k) {
            int bin = NB - 1 - (t * CHUNK + k);
            s += h[bin];
        }
        ps[t] = s;
        __syncthreads();
        for (int off = 1; off < 256; off <<= 1) {
            unsigned v = (t >= off) ? ps[t - off] : 0u;
            __syncthreads();
            ps[t] += v;
            __syncthreads();
        }
        unsigned excl = (t == 0) ? 0u : ps[t - 1];
        unsigned incl = ps[t];
        if (excl < Kp && Kp <= incl) {
            unsigned run = excl;
            for (int k = 0; k < CHUNK; ++k) {
                int bin = NB - 1 - (t * CHUNK + k);
                unsigned c = h[bin];
                if (run + c >= Kp) {
                    unsigned npf = prefix | ((unsigned)bin << SHIFT);
                    state[b * 2 + 0] = npf;
                    state[b * 2 + 1] = Kp - run;
                    if (SHIFT == 0) thr[b] = __uint_as_float(npf);
                    break;
                }
                run += c;
            }
        }
        __syncthreads();
    }
}

__global__ void tw_matvec(const float4* __restrict__ jdata, const float* __restrict__ thr,
                          const float* alphap, const float* ksp, const float* kbp,
                          const float* sensp, float* __restrict__ out, int N) {
    const int b = blockIdx.y;
    const int wid = threadIdx.x >> 6;
    const int lane = threadIdx.x & 63;
    const int i = blockIdx.x * 4 + wid;

    float4 mine = jdata[b * N + i];
    float amp_i = mine.x, phi_i = mine.y;
    const float sens = *sensp;
    const float expo = tw_expo(ksp, kbp);
    const float T = thr[b];
    const float alpha = *alphap;

    float ar = 0.0f, ai = 0.0f;
    for (int j = lane; j < N; j += 64) {
        float4 jd = jdata[b * N + j];
        float R = tw_R(amp_i, phi_i, jd.x, jd.y, sens, expo);
        if (R >= T) { ar += R * jd.z; ai += R * jd.w; }
    }
    for (int off = 32; off; off >>= 1) {
        ar += __shfl_down(ar, off);
        ai += __shfl_down(ai, off);
    }
    if (lane == 0) {
        out[(b * N + i) * 2 + 0] = alpha * ar;
        out[(b * N + i) * 2 + 1] = alpha * ai;
    }
}

// ---------------- launch ----------------

static inline size_t tw_align(size_t x) { return (x + 255) & ~(size_t)255; }

extern "C" void kernel_launch(void* const* d_in, const int* in_sizes, int n_in,
                              void* d_out, int out_size, void* d_ws, size_t ws_size,
                              hipStream_t stream) {
    const float* zr    = (const float*)d_in[0];
    const float* zi    = (const float*)d_in[1];
    const float* alpha = (const float*)d_in[2];
    const float* ks    = (const float*)d_in[3];
    const float* kb    = (const float*)d_in[4];
    const float* sens  = (const float*)d_in[5];
    float* out = (float*)d_out;

    const int N = TW_N;
    const int B = in_sizes[0] / N;
    const int total = B * N;

    long long tot2 = (long long)N * N;
    long long kv = (long long)8 * N;
    if (kv < 1) kv = 1;
    if (kv > tot2 - 1) kv = tot2 - 1;
    const unsigned K = (unsigned)(kv + 1);  // rank of threshold value (1-based)

    char* ws = (char*)d_ws;

    // layout: [hP(8 partials)|hA|hB|hC|cnt|ccount|bar <- zeroed | jfast | jexact | cidx | cval | seg]
    size_t o_hP     = 0;
    size_t o_hA     = o_hP + (size_t)TW_NPART * B * 2048 * sizeof(unsigned);
    size_t o_hB     = o_hA + (size_t)B * 4096 * sizeof(unsigned);
    size_t o_hC     = o_hB + (size_t)B * 4096 * sizeof(unsigned);
    size_t o_cnt    = o_hC + (size_t)B * 256 * sizeof(unsigned);
    size_t o_ccount = o_cnt + (size_t)B * TW_TBLK * sizeof(unsigned);
    size_t o_bar    = o_ccount + (size_t)B * sizeof(unsigned);
    size_t o_zero_end = o_bar + 2 * sizeof(unsigned);
    size_t o_jfast  = tw_align(o_zero_end);
    size_t o_jexact = tw_align(o_jfast + (size_t)B * N * sizeof(float2));
    size_t o_cidx   = tw_align(o_jexact + (size_t)B * N * sizeof(float4));
    size_t o_cval   = tw_align(o_cidx + (size_t)B * TW_CAND_CAP * sizeof(unsigned));
    size_t o_seg    = tw_align(o_cval + (size_t)B * TW_CAND_CAP * sizeof(float));
    size_t o_end    = o_seg + (size_t)B * TW_TBLK * TW_SEGCAP * sizeof(unsigned);

    if (ws_size >= o_end) {
        unsigned* hP     = (unsigned*)(ws + o_hP);
        unsigned* hA     = (unsigned*)(ws + o_hA);
        unsigned* hB     = (unsigned*)(ws + o_hB);
        unsigned* hC     = (unsigned*)(ws + o_hC);
        unsigned* cnt    = (unsigned*)(ws + o_cnt);
        unsigned* ccount = (unsigned*)(ws + o_ccount);
        unsigned* bar    = (unsigned*)(ws + o_bar);
        float2*   jfast  = (float2*)(ws + o_jfast);
        float4*   jexact = (float4*)(ws + o_jexact);
        unsigned* cidx   = (unsigned*)(ws + o_cidx);
        float*    cval   = (float*)(ws + o_cval);
        unsigned* seg    = (unsigned*)(ws + o_seg);

        const int zero_words = (int)(o_zero_end / sizeof(unsigned));
        const int out_words  = out_size;

        // ---- Round-12 path: memset + persistent kernel, if co-resident ----
        static int persist_max = -1;
        if (persist_max < 0) {
            int perCU = 0, nCU = 0, dev = 0;
            (void)hipGetDevice(&dev);
            if (hipOccupancyMaxActiveBlocksPerMultiprocessor(
                    &perCU, (const void*)tw_persist, 256, 0) != hipSuccess) perCU = 0;
            if (hipDeviceGetAttribute(&nCU, hipDeviceAttributeMultiprocessorCount,
                                      dev) != hipSuccess) nCU = 0;
            persist_max = perCU * nCU;
        }
        if (persist_max >= TW_TBLK * B) {
            (void)hipMemsetAsync(ws, 0, o_zero_end, stream);
            tw_persist<<<dim3(TW_TBLK, B), 256, 0, stream>>>(
                zr, zi, alpha, ks, kb, sens, out, out_words,
                hP, hA, hB, hC, cnt, ccount, jfast, jexact,
                cidx, cval, seg, bar, N, B, total, K);
            return;
        }

        // ---- Round-10 7-kernel fallback ----
        tw_init<<<128, 256, 0, stream>>>(zr, zi, jfast, jexact, (unsigned*)ws, zero_words,
                                         out, out_words, ks, kb, total);

        dim3 tgrid(TW_TBLK, B);
        tw_histW<<<tgrid, 256, 0, stream>>>(jfast, hP, sens, N, B);
        tw_collectW<<<tgrid, 256, 0, stream>>>(jfast, hP, seg, cnt, sens, N, B, K);
        tw_gexact<<<tgrid, 256, 0, stream>>>(seg, cnt, cidx, cval, jexact, hA, ccount,
                                             ks, kb, sens, N, TW_TBLK, TW_CAND_CAP);
        tw_chist1f<<<dim3(TW_CBLK, B), 256, 0, stream>>>(cval, cidx, ccount, hA, hB, K, TW_CAND_CAP);
        tw_chist2f<<<dim3(TW_CBLK, B), 256, 0, stream>>>(cval, cidx, ccount, hA, hB, hC, K, TW_CAND_CAP);
        tw_scatterf<<<dim3(TW_SBLK, B), 256, 0, stream>>>(cval, cidx, ccount, hA, hB, hC,
                                                          jexact, alpha, out, K, N, TW_CAND_CAP);
        return;
    }

    // ---- legacy fallback (round-1 pipeline) ----
    size_t l_jdata = 0;
    size_t l_h1 = l_jdata + (size_t)B * N * sizeof(float4);
    size_t l_h2 = l_h1 + (size_t)B * 4096 * sizeof(unsigned);
    size_t l_h3 = l_h2 + (size_t)B * 4096 * sizeof(unsigned);
    size_t l_state = l_h3 + (size_t)B * 256 * sizeof(unsigned);
    size_t l_thr = l_state + (size_t)B * 2 * sizeof(unsigned);
    size_t l_end = l_thr + (size_t)B * sizeof(float);

    float4* jdata = (float4*)(ws + l_jdata);
    unsigned* h1 = (unsigned*)(ws + l_h1);
    unsigned* h2 = (unsigned*)(ws + l_h2);
    unsigned* h3 = (unsigned*)(ws + l_h3);
    unsigned* state = (unsigned*)(ws + l_state);
    float* thr = (float*)(ws + l_thr);

    (void)hipMemsetAsync(ws + l_h1, 0, l_end - l_h1, stream);

    tw_precompute<<<(total + 255) / 256, 256, 0, stream>>>(zr, zi, jdata, state, total, B, K);

    dim3 hgrid(N / 256, N / 256, B);
    tw_hist<1><<<hgrid, 256, 0, stream>>>(jdata, h1, state, ks, kb, sens, N);
    tw_scan<4096, 20><<<1, 256, 0, stream>>>(h1, state, thr, B);
    tw_hist<2><<<hgrid, 256, 0, stream>>>(jdata, h2, state, ks, kb, sens, N);
    tw_scan<4096, 8><<<1, 256, 0, stream>>>(h2, state, thr, B);
    tw_hist<3><<<hgrid, 256, 0, stream>>>(jdata, h3, state, ks, kb, sens, N);
    tw_scan<256, 0><<<1, 256, 0, stream>>>(h3, state, thr, B);

    tw_matvec<<<dim3(N / 4, B), 256, 0, stream>>>(jdata, thr, alpha, ks, kb, sens, out, N);
}

// Round 3
// 107.737 us; speedup vs baseline: 1.0069x; 1.0069x over previous
//
#include <hip/hip_runtime.h>
#include <math.h>

// TwistorResonance: B=2, N=4096 (hardcoded N; B derived from in_sizes).
// R_ij = |z_i||z_j| * |cos((phi_i-phi_j)*sens)|^expo, top-(8N+1) threshold over
// flattened N^2, keep R>=thr, out = alpha * [R@zr, R@zi] stacked last-dim.
//
// Round-13: persistent kernel, 4 phases / 3 PER-BATCH barriers (was 7/6).
//   Round-12 post-mortem: fusing dispatches bought ~0 because a device-wide
//   sync costs ~12us whether it's a dispatch boundary or an in-kernel barrier
//   (wave drain + cross-XCD L2 wb/inv + refill). Intrinsic work ~25-30us
//   (round-11 VALUBusy 2.1% x 953us). So: cut sync COUNT and coherence volume.
//   S0 histW   : recompute tiles in LDS (no jfast array), w-hist -> hP,
//                zero out.                                   -- bar(gen1)
//   S1 collect : inline wmin (guard 2 bins); candidates -> OWN uint2 segment
//                {pij, exact libm val bits}; 65536-bin hist of top-16 bits
//                (global atomics) + 256-bin coarse (LDS 4-way).-- bar(gen2)
//   S2 histLo  : inline 2-level scan (coarse+fine) -> bin16; filtered low-16
//                hist (global) + coarse (LDS).                -- bar(gen3)
//   S3 scatter : inline scans -> exact 32-bit thr; scatter own segment,
//                zr/zi loaded directly.
//   Selection exact (8+8+8+8 radix recursion, weights diag=1/offdiag=2),
//   values bit-identical (same tw_R libm chain) -> absmax 0.0.
//   Per-batch barriers: batches share nothing; 416-block barriers, phases of
//   the two batches overlap. Occupancy gate -> proven round-10 fallback.

#define TW_N 4096
#define TW_TILE 64
#define TW_NBLK (TW_N / TW_TILE)                 // 64
#define TW_TRI (TW_NBLK * (TW_NBLK + 1) / 2)     // 2080
#define TW_TPB 5                                 // tri-tiles per block
#define TW_TBLK (TW_TRI / TW_TPB)                // 416 blocks per batch
#define TW_SEGCAP (TW_TPB * TW_TILE * TW_TILE)   // 20480: structural max
#define TW_NPART 8                               // partial global hists
#define TW_CAND_CAP (1 << 19)
#define TW_CBLK 64
#define TW_SBLK 128

__device__ __forceinline__ float tw_softplus(float x) {
    return fmaxf(x, 0.0f) + log1pf(expf(-fabsf(x)));
}

__device__ __forceinline__ float tw_expo(const float* ksp, const float* kbp) {
    return tw_softplus(*ksp) + tw_softplus(*kbp) + 1e-6f;
}

// exact path (libm) — bit-identical to rounds 1-12 (absmax 0.0 vs numpy)
__device__ __forceinline__ float tw_R(float amp_i, float phi_i,
                                      float amp_j, float phi_j,
                                      float sens, float expo) {
    float dphi = phi_i - phi_j;
    float c = fabsf(cosf(dphi * sens));
    c = fmaxf(c, 1e-10f);
    float ph = powf(c, expo);
    return amp_i * amp_j * ph;
}

// triangular tile decode: tiles (bi,bj), bi<=bj, row-major in bi.
__device__ __forceinline__ int tw_rowstart(int bi) {
    return bi * TW_NBLK - ((bi * (bi - 1)) >> 1);
}
__device__ __forceinline__ void tw_decode(int tt, int& bi, int& bj) {
    const float A = (float)(2 * TW_NBLK + 1);
    float disc = A * A - 8.0f * (float)tt;
    int b = (int)((A - sqrtf(disc)) * 0.5f);
    if (b < 0) b = 0;
    if (b > TW_NBLK - 1) b = TW_NBLK - 1;
    while (b + 1 <= TW_NBLK - 1 && tw_rowstart(b + 1) <= tt) ++b;
    while (b > 0 && tw_rowstart(b) > tt) --b;
    bi = b;
    bj = b + (tt - tw_rowstart(b));
}

// ---- minimal device-wide barrier (co-resident blocks, plain launch) ----
// bar[0]: monotonic arrival counter; bar[1]: generation (memset to 0).
// Release fence: writeback dirty L2 (own segments) so post-inv re-reads hit
// LLC-correct data; acquire fence: invalidate L1/L2 (hist visibility).
__device__ __forceinline__ void tw_gbar(unsigned* bar, unsigned target, unsigned gen) {
    __syncthreads();
    __builtin_amdgcn_fence(__ATOMIC_RELEASE, "agent");
    if (threadIdx.x == 0) {
        unsigned v = __hip_atomic_fetch_add(&bar[0], 1u, __ATOMIC_RELAXED,
                                            __HIP_MEMORY_SCOPE_AGENT);
        if (v + 1u == target) {
            __hip_atomic_store(&bar[1], gen, __ATOMIC_RELAXED,
                               __HIP_MEMORY_SCOPE_AGENT);
        } else {
            while (__hip_atomic_load(&bar[1], __ATOMIC_RELAXED,
                                     __HIP_MEMORY_SCOPE_AGENT) < gen)
                __builtin_amdgcn_s_sleep(2);
        }
    }
    __syncthreads();
    __builtin_amdgcn_fence(__ATOMIC_ACQUIRE, "agent");
}

// block-cooperative top-down radix scan over NB-bin hist; all 256 threads.
template <int NB>
__device__ void tw_scan_dev(const unsigned* __restrict__ h, unsigned Kp_in,
                            unsigned& bin_out, unsigned& kp_out) {
    __shared__ unsigned ps_[256];
    __shared__ unsigned shb_, shk_;
    constexpr int CHUNK = NB / 256;
    const int t = threadIdx.x;
    __syncthreads();                         // protect static-shared reuse
    unsigned s = 0;
    for (int k = 0; k < CHUNK; ++k) s += h[NB - 1 - (t * CHUNK + k)];
    ps_[t] = s;
    __syncthreads();
    for (int off = 1; off < 256; off <<= 1) {
        unsigned v = (t >= off) ? ps_[t - off] : 0u;
        __syncthreads();
        ps_[t] += v;
        __syncthreads();
    }
    unsigned excl = (t == 0) ? 0u : ps_[t - 1];
    if (excl < Kp_in && Kp_in <= ps_[t]) {
        unsigned run = excl;
        for (int k = 0; k < CHUNK; ++k) {
            int bin = NB - 1 - (t * CHUNK + k);
            unsigned c = h[bin];
            if (run + c >= Kp_in) { shb_ = (unsigned)bin; shk_ = Kp_in - run; break; }
            run += c;
        }
    }
    __syncthreads();
    bin_out = shb_; kp_out = shk_;
}

// block-cooperative wmin from 8 partial 2048-bin hists (guard 2 bins).
__device__ float tw_wmin_dev(const unsigned* __restrict__ histp, int b, int B, unsigned K) {
    __shared__ unsigned ps_[256];
    __shared__ unsigned shm_;
    const int t = threadIdx.x;
    unsigned s = 0;
    for (int k = 0; k < 8; ++k) {
        int bin = 2047 - (t * 8 + k);
        for (int p = 0; p < TW_NPART; ++p)
            s += histp[((size_t)p * B + b) * 2048 + bin];
    }
    ps_[t] = s;
    __syncthreads();
    for (int off = 1; off < 256; off <<= 1) {
        unsigned v = (t >= off) ? ps_[t - off] : 0u;
        __syncthreads();
        ps_[t] += v;
        __syncthreads();
    }
    unsigned excl = (t == 0) ? 0u : ps_[t - 1];
    if (excl < K && K <= ps_[t]) {
        unsigned run = excl;
        for (int k = 0; k < 8; ++k) {
            int bin = 2047 - (t * 8 + k);
            unsigned c = 0;
            for (int p = 0; p < TW_NPART; ++p)
                c += histp[((size_t)p * B + b) * 2048 + bin];
            if (run + c >= K) {
                int mb = bin - 2; if (mb < 0) mb = 0;
                shm_ = (unsigned)mb << 20;
                break;
            }
            run += c;
        }
    }
    __syncthreads();
    return __uint_as_float(shm_);
}

// candidate weight: off-diagonal TILE pairs represent (i,j) and (j,i) -> 2
__device__ __forceinline__ unsigned tw_w(unsigned pij) {
    return ((pij >> 18) == ((pij >> 6) & 63u)) ? 1u : 2u;
}

// ================= Round-13 persistent kernel: 4 phases, 3 barriers =========
// LDS: s_lh 32KB + 6x64 tile floats (1.5KB) + scan/wmin statics (~2KB) ~36KB
// -> 4 blocks/CU; grid 416*B co-resident (gated host-side).
__global__ void __launch_bounds__(256, 4)
tw_p3(const float* zr, const float* zi,
      const float* alphap, const float* ksp, const float* kbp, const float* sensp,
      float* out, int out_words,
      unsigned* hP, unsigned* h16c, unsigned* h16, unsigned* hLoc, unsigned* hLo,
      unsigned* bar, uint2* seg, int N, int B, unsigned K) {
    __shared__ unsigned s_lh[2048 * 4];
    __shared__ float s_iv[TW_TILE], s_ia[TW_TILE], s_ip[TW_TILE];
    __shared__ float s_jv[TW_TILE], s_ja[TW_TILE], s_jp[TW_TILE];
    __shared__ unsigned s_cn;

    const int tid = threadIdx.x;
    const int b = blockIdx.y;
    const int bx = blockIdx.x;
    const int jj = tid & 63, r0 = tid >> 6, rep = tid & 3;
    const float sens = *sensp;
    const float expo = tw_expo(ksp, kbp);
    const float inv_e = 1.0f / expo;
    unsigned* mybar = bar + b * 2;
    uint2* sg = seg + (size_t)(b * TW_TBLK + bx) * TW_SEGCAP;

    // ---- S0: zero out + pair sweep #1 -> 2048-bin w hist (hP) ----
    {
        const int bid = b * gridDim.x + bx;
        const int gs = gridDim.x * gridDim.y * 256;
        for (int k = bid * 256 + tid; k < out_words; k += gs) out[k] = 0.0f;
        for (int k = tid; k < 2048 * 4; k += 256) s_lh[k] = 0u;
        int bi, bj;
        tw_decode(bx * TW_TPB, bi, bj);
        int cur = -1;
        for (int s = 0; s < TW_TPB; ++s) {
            __syncthreads();
            if (tid < TW_TILE) {
                int g = b * N + bj * TW_TILE + tid;
                float r = zr[g], m = zi[g];
                float amp = sqrtf(r * r + m * m);
                s_jv[tid] = powf(amp, inv_e);
                s_jp[tid] = atan2f(m, r);
            } else if (tid < 2 * TW_TILE && bi != cur) {
                int t = tid - TW_TILE;
                int g = b * N + bi * TW_TILE + t;
                float r = zr[g], m = zi[g];
                float amp = sqrtf(r * r + m * m);
                s_iv[t] = powf(amp, inv_e);
                s_ip[t] = atan2f(m, r);
            }
            cur = bi;
            __syncthreads();
            float vi[16], ph[16];
#pragma unroll
            for (int k = 0; k < 16; ++k) {
                int il = r0 + (k << 2);            // wave-uniform LDS broadcast
                vi[k] = s_iv[il]; ph[k] = s_ip[il];
            }
            const float vj = s_jv[jj], pj = s_jp[jj];
            const unsigned inc = (bi == bj) ? 1u : 2u;
#pragma unroll
            for (int k = 0; k < 16; ++k) {
                float w = vi[k] * vj * fabsf(__cosf((ph[k] - pj) * sens));
                atomicAdd(&s_lh[((__float_as_uint(w) >> 20) << 2) + rep], inc);
            }
            ++bj;
            if (bj >= TW_NBLK) { ++bi; bj = bi; }
        }
        __syncthreads();
        unsigned* hp = hP + ((size_t)(bx & (TW_NPART - 1)) * B + b) * 2048;
        const int rot = (int)((bx * 191u + b * 977u) & 2047u);
        for (int kk = tid; kk < 2048; kk += 256) {
            int k = (kk + rot) & 2047;
            unsigned v = s_lh[k * 4] + s_lh[k * 4 + 1] + s_lh[k * 4 + 2] + s_lh[k * 4 + 3];
            if (v) atomicAdd(&hp[k], v);
        }
    }
    tw_gbar(mybar, TW_TBLK * 1u, 1u);

    // ---- S1: collect into own segment + exact libm val + top-16 hist ----
    {
        const float wmin = tw_wmin_dev(hP, b, B, K);
        if (tid == 0) s_cn = 0u;
        for (int k = tid; k < 1024; k += 256) s_lh[k] = 0u;   // 256-bin coarse x4
        int bi, bj;
        tw_decode(bx * TW_TPB, bi, bj);
        int cur = -1;
        for (int s = 0; s < TW_TPB; ++s) {
            __syncthreads();
            if (tid < TW_TILE) {
                int g = b * N + bj * TW_TILE + tid;
                float r = zr[g], m = zi[g];
                float amp = sqrtf(r * r + m * m);
                s_ja[tid] = amp;
                s_jv[tid] = powf(amp, inv_e);
                s_jp[tid] = atan2f(m, r);
            } else if (tid < 2 * TW_TILE && bi != cur) {
                int t = tid - TW_TILE;
                int g = b * N + bi * TW_TILE + t;
                float r = zr[g], m = zi[g];
                float amp = sqrtf(r * r + m * m);
                s_ia[t] = amp;
                s_iv[t] = powf(amp, inv_e);
                s_ip[t] = atan2f(m, r);
            }
            cur = bi;
            __syncthreads();
            const float vj = s_jv[jj], pj = s_jp[jj], aj = s_ja[jj];
            const unsigned ib = (unsigned)(bi * TW_TILE);
            const unsigned jg = (unsigned)(bj * TW_TILE) + (unsigned)jj;
            const unsigned wg = (bi == bj) ? 1u : 2u;
#pragma unroll
            for (int k = 0; k < 16; ++k) {
                const int il = r0 + (k << 2);
                float w = s_iv[il] * vj * fabsf(__cosf((s_ip[il] - pj) * sens));
                if (w >= wmin) {
                    float val = tw_R(s_ia[il], s_ip[il], aj, pj, sens, expo);
                    unsigned bits = __float_as_uint(val);
                    unsigned pij = ((ib + (unsigned)il) << 12) | jg;
                    unsigned p = atomicAdd(&s_cn, 1u);        // LDS ticket
                    sg[p] = make_uint2(pij, bits);
                    atomicAdd(&h16[((size_t)b << 16) + (bits >> 16)], wg);
                    atomicAdd(&s_lh[((bits >> 24) << 2) + rep], wg);
                }
            }
            ++bj;
            if (bj >= TW_NBLK) { ++bi; bj = bi; }
        }
        __syncthreads();
        if (tid < 256) {
            unsigned v = s_lh[tid * 4] + s_lh[tid * 4 + 1] + s_lh[tid * 4 + 2] + s_lh[tid * 4 + 3];
            if (v) atomicAdd(&h16c[b * 256 + tid], v);
        }
    }
    tw_gbar(mybar, TW_TBLK * 2u, 2u);

    // ---- S2: inline scan -> bin16; filtered low-16 hist ----
    {
        unsigned c8, Kp1, f8, Kp2;
        tw_scan_dev<256>(h16c + b * 256, K, c8, Kp1);
        tw_scan_dev<256>(h16 + ((size_t)b << 16) + (c8 << 8), Kp1, f8, Kp2);
        const unsigned bin16 = (c8 << 8) | f8;
        for (int k = tid; k < 1024; k += 256) s_lh[k] = 0u;
        const unsigned cn = s_cn;
        __syncthreads();
        for (unsigned k = tid; k < cn; k += 256) {
            uint2 u = sg[k];
            if ((u.y >> 16) == bin16) {
                unsigned wg = tw_w(u.x);
                atomicAdd(&hLo[((size_t)b << 16) + (u.y & 0xFFFFu)], wg);
                atomicAdd(&s_lh[(((u.y >> 8) & 0xFFu) << 2) + rep], wg);
            }
        }
        __syncthreads();
        if (tid < 256) {
            unsigned v = s_lh[tid * 4] + s_lh[tid * 4 + 1] + s_lh[tid * 4 + 2] + s_lh[tid * 4 + 3];
            if (v) atomicAdd(&hLoc[b * 256 + tid], v);
        }
    }
    tw_gbar(mybar, TW_TBLK * 3u, 3u);

    // ---- S3: inline scans -> exact 32-bit thr; scatter own segment ----
    {
        unsigned c8, Kp1, f8, Kp2, cL, Kp3, fL, Kp4;
        tw_scan_dev<256>(h16c + b * 256, K, c8, Kp1);
        tw_scan_dev<256>(h16 + ((size_t)b << 16) + (c8 << 8), Kp1, f8, Kp2);
        tw_scan_dev<256>(hLoc + b * 256, Kp2, cL, Kp3);
        tw_scan_dev<256>(hLo + ((size_t)b << 16) + (cL << 8), Kp3, fL, Kp4);
        const float T = __uint_as_float((((c8 << 8) | f8) << 16) | (cL << 8) | fL);
        const float alpha = *alphap;
        const unsigned cn = s_cn;
        for (unsigned k = tid; k < cn; k += 256) {
            uint2 u = sg[k];
            const float v = __uint_as_float(u.y);
            if (v < T) continue;
            const unsigned i = u.x >> 12, j = u.x & 4095u;
            float zjr = zr[b * N + j], zji = zi[b * N + j];
            atomicAdd(&out[(size_t)(b * N + i) * 2 + 0], alpha * v * zjr);
            atomicAdd(&out[(size_t)(b * N + i) * 2 + 1], alpha * v * zji);
            if ((u.x >> 18) != ((u.x >> 6) & 63u)) {   // off-diagonal tile -> mirror
                float zir = zr[b * N + i], zii = zi[b * N + i];
                atomicAdd(&out[(size_t)(b * N + j) * 2 + 0], alpha * v * zir);
                atomicAdd(&out[(size_t)(b * N + j) * 2 + 1], alpha * v * zii);
            }
        }
    }
}

// ================= Round-10 7-kernel path (fallback) =================

// ---- 0. init ----
__global__ void tw_init(const float* __restrict__ zr, const float* __restrict__ zi,
                        float2* __restrict__ jfast, float4* __restrict__ jexact,
                        unsigned* __restrict__ zero_base, int zero_words,
                        float* __restrict__ out, int out_words,
                        const float* ksp, const float* kbp, int total) {
    const int idx = blockIdx.x * blockDim.x + threadIdx.x;
    const int stride = gridDim.x * blockDim.x;
    for (int k = idx; k < zero_words; k += stride) zero_base[k] = 0u;
    for (int k = idx; k < out_words; k += stride) out[k] = 0.0f;
    if (idx < total) {
        float r = zr[idx], m = zi[idx];
        float amp = sqrtf(r * r + m * m);
        float phi = atan2f(m, r);
        jexact[idx] = make_float4(amp, phi, r, m);
        float e = tw_expo(ksp, kbp);
        jfast[idx] = make_float2(powf(amp, 1.0f / e), phi);   // v = amp^(1/e)
    }
}

// ---- 1. 4-way lane-replicated 2048-bin hist of w float-bits ----
__global__ void tw_histW(const float2* __restrict__ jf, unsigned* __restrict__ histp,
                         const float* __restrict__ sensp, int N, int B) {
    __shared__ float s_jv[TW_TILE], s_jp[TW_TILE];
    __shared__ unsigned lh[2048 * 4];            // lh[bin*4 + rep]: distinct banks
    const int b = blockIdx.y, tid = threadIdx.x;
    const int jj = tid & 63, r0 = tid >> 6;
    const int rep = tid & 3;
    for (int k = tid; k < 2048 * 4; k += 256) lh[k] = 0u;
    const float sens = *sensp;
    int bi, bj;
    tw_decode(blockIdx.x * TW_TPB, bi, bj);
    for (int s = 0; s < TW_TPB; ++s) {
        __syncthreads();
        if (tid < TW_TILE) {
            float2 w = jf[b * N + bj * TW_TILE + tid];
            s_jv[tid] = w.x; s_jp[tid] = w.y;
        }
        float vi[16], ph[16];
#pragma unroll
        for (int k = 0; k < 16; ++k) {
            float2 v = jf[b * N + bi * TW_TILE + r0 + (k << 2)];  // wave-uniform
            vi[k] = v.x; ph[k] = v.y;
        }
        __syncthreads();
        const float vj = s_jv[jj], pj = s_jp[jj];
        const unsigned inc = (bi == bj) ? 1u : 2u;
#pragma unroll
        for (int k = 0; k < 16; ++k) {
            float w = vi[k] * vj * fabsf(__cosf((ph[k] - pj) * sens));
            atomicAdd(&lh[((__float_as_uint(w) >> 20) << 2) + rep], inc);
        }
        ++bj;
        if (bj >= TW_NBLK) { ++bi; bj = bi; }
    }
    __syncthreads();
    unsigned* hp = histp + ((size_t)(blockIdx.x & (TW_NPART - 1)) * B + b) * 2048;
    const int rot = (int)((blockIdx.x * 191u + b * 977u) & 2047u);
    for (int kk = tid; kk < 2048; kk += 256) {
        int k = (kk + rot) & 2047;
        unsigned v = lh[k * 4] + lh[k * 4 + 1] + lh[k * 4 + 2] + lh[k * 4 + 3];
        if (v) atomicAdd(&hp[k], v);
    }
}

// ---- 2. collect (inline wmin): w >= wmin -> private per-block segment ----
__global__ void tw_collectW(const float2* __restrict__ jf, const unsigned* __restrict__ histp,
                            unsigned* __restrict__ seg, unsigned* __restrict__ cnt,
                            const float* __restrict__ sensp, int N, int B, unsigned K) {
    __shared__ float s_jv[TW_TILE], s_jp[TW_TILE];
    __shared__ unsigned cn;
    const int b = blockIdx.y, tid = threadIdx.x;
    const int jj = tid & 63, r0 = tid >> 6;
    const float wmin = tw_wmin_dev(histp, b, B, K);
    if (tid == 0) cn = 0u;
    const float sens = *sensp;
    const int gid = b * TW_TBLK + blockIdx.x;
    unsigned* sg = seg + (size_t)gid * TW_SEGCAP;
    int bi, bj;
    tw_decode(blockIdx.x * TW_TPB, bi, bj);
    for (int s = 0; s < TW_TPB; ++s) {
        __syncthreads();
        if (tid < TW_TILE) {
            float2 w = jf[b * N + bj * TW_TILE + tid];
            s_jv[tid] = w.x; s_jp[tid] = w.y;
        }
        float vi[16], ph[16];
#pragma unroll
        for (int k = 0; k < 16; ++k) {
            float2 v = jf[b * N + bi * TW_TILE + r0 + (k << 2)];
            vi[k] = v.x; ph[k] = v.y;
        }
        __syncthreads();
        const float vj = s_jv[jj], pj = s_jp[jj];
        const unsigned ib = (unsigned)(bi * TW_TILE);
        const unsigned jg = (unsigned)(bj * TW_TILE) + (unsigned)jj;
#pragma unroll
        for (int k = 0; k < 16; ++k) {
            float w = vi[k] * vj * fabsf(__cosf((ph[k] - pj) * sens));
            if (w >= wmin) {
                unsigned p = atomicAdd(&cn, 1u);   // LDS ticket, block-local
                sg[p] = ((ib + (unsigned)(r0 + (k << 2))) << 12) | jg;
            }
        }
        ++bj;
        if (bj >= TW_NBLK) { ++bi; bj = bi; }
    }
    __syncthreads();
    if (tid == 0) cnt[gid] = cn;
}

// ---- 3. FUSED inline-offset + gather + exact libm + radix phase0 hist ----
__global__ void tw_gexact(const unsigned* __restrict__ seg, const unsigned* __restrict__ cnt,
                          unsigned* __restrict__ cand_idx, float* __restrict__ cand_val,
                          const float4* __restrict__ jdata, unsigned* __restrict__ histA,
                          unsigned* __restrict__ ccount,
                          const float* ksp, const float* kbp, const float* sensp,
                          int N, int perb, int cap) {
    __shared__ unsigned lh[4096];
    __shared__ unsigned red[256];
    const int b = blockIdx.y, tid = threadIdx.x;
    for (int k = tid; k < 4096; k += 256) lh[k] = 0u;
    // exclusive offset of this block within batch b (replaces cscan)
    unsigned partial = 0;
    for (int k = tid; k < (int)blockIdx.x; k += 256) partial += cnt[b * perb + k];
    red[tid] = partial;
    __syncthreads();
    for (int off = 128; off; off >>= 1) {
        if (tid < off) red[tid] += red[tid + off];
        __syncthreads();
    }
    const unsigned dbase = red[0];
    const int gid = b * perb + blockIdx.x;
    const unsigned n = cnt[gid];
    if (blockIdx.x == perb - 1 && tid == 0) ccount[b] = dbase + n;
    const unsigned* src = seg + (size_t)gid * TW_SEGCAP;
    const float sens = *sensp;
    const float expo = tw_expo(ksp, kbp);
    __syncthreads();
    for (unsigned k = tid; k < n; k += 256) {
        unsigned pij = src[k];
        unsigned d = dbase + k;
        if (d >= (unsigned)cap) continue;
        const unsigned i = pij >> 12, j = pij & 4095u;
        float4 di = jdata[b * N + i];
        float4 dj = jdata[b * N + j];
        float val = tw_R(di.x, di.y, dj.x, dj.y, sens, expo);
        cand_idx[(size_t)b * cap + d] = pij;
        cand_val[(size_t)b * cap + d] = val;
        atomicAdd(&lh[__float_as_uint(val) >> 20], tw_w(pij));
    }
    __syncthreads();
    for (int k = tid; k < 4096; k += 256) {
        unsigned v = lh[k];
        if (v) atomicAdd(&histA[b * 4096 + k], v);
    }
}

// ---- 4. chist phase1 with inline scanA ----
__global__ void tw_chist1f(const float* __restrict__ cand_val, const unsigned* __restrict__ cand_idx,
                           const unsigned* __restrict__ ccount, const unsigned* __restrict__ histA,
                           unsigned* __restrict__ histB, unsigned K, int cap) {
    __shared__ unsigned lh[4096];
    const int b = blockIdx.y, tid = threadIdx.x;
    unsigned binA, KpA;
    tw_scan_dev<4096>(histA + (size_t)b * 4096, K, binA, KpA);
    for (int k = tid; k < 4096; k += 256) lh[k] = 0u;
    unsigned nb = ccount[b]; if (nb > (unsigned)cap) nb = (unsigned)cap;
    const float* cv = cand_val + (size_t)b * cap;
    const unsigned* ci = cand_idx + (size_t)b * cap;
    __syncthreads();
    const unsigned stride = gridDim.x * 256;
    for (unsigned idx = blockIdx.x * 256 + tid; idx < nb; idx += stride) {
        unsigned bits = __float_as_uint(cv[idx]);
        if ((bits >> 20) == binA) atomicAdd(&lh[(bits >> 8) & 0xFFFu], tw_w(ci[idx]));
    }
    __syncthreads();
    for (int k = tid; k < 4096; k += 256) {
        unsigned v = lh[k];
        if (v) atomicAdd(&histB[b * 4096 + k], v);
    }
}

// ---- 5. chist phase2 with inline scanA+scanB ----
__global__ void tw_chist2f(const float* __restrict__ cand_val, const unsigned* __restrict__ cand_idx,
                           const unsigned* __restrict__ ccount, const unsigned* __restrict__ histA,
                           const unsigned* __restrict__ histB, unsigned* __restrict__ histC,
                           unsigned K, int cap) {
    __shared__ unsigned lh[256];
    const int b = blockIdx.y, tid = threadIdx.x;
    unsigned binA, KpA, binB, KpB;
    tw_scan_dev<4096>(histA + (size_t)b * 4096, K, binA, KpA);
    tw_scan_dev<4096>(histB + (size_t)b * 4096, KpA, binB, KpB);
    if (tid < 256) lh[tid] = 0u;
    unsigned nb = ccount[b]; if (nb > (unsigned)cap) nb = (unsigned)cap;
    const unsigned pf24 = (binA << 12) | binB;
    const float* cv = cand_val + (size_t)b * cap;
    const unsigned* ci = cand_idx + (size_t)b * cap;
    __syncthreads();
    const unsigned stride = gridDim.x * 256;
    for (unsigned idx = blockIdx.x * 256 + tid; idx < nb; idx += stride) {
        unsigned bits = __float_as_uint(cv[idx]);
        if ((bits >> 8) == pf24) atomicAdd(&lh[bits & 0xFFu], tw_w(ci[idx]));
    }
    __syncthreads();
    if (tid < 256) {
        unsigned v = lh[tid];
        if (v) atomicAdd(&histC[b * 256 + tid], v);
    }
}

// ---- 6. scatter with inline scanA+scanB+scanC -> exact thr ----
__global__ void tw_scatterf(const float* __restrict__ cand_val, const unsigned* __restrict__ cand_idx,
                            const unsigned* __restrict__ ccount, const unsigned* __restrict__ histA,
                            const unsigned* __restrict__ histB, const unsigned* __restrict__ histC,
                            const float4* __restrict__ jdata, const float* alphap,
                            float* __restrict__ out, unsigned K, int N, int cap) {
    const int b = blockIdx.y;
    unsigned binA, KpA, binB, KpB, binC, KpC;
    tw_scan_dev<4096>(histA + (size_t)b * 4096, K, binA, KpA);
    tw_scan_dev<4096>(histB + (size_t)b * 4096, KpA, binB, KpB);
    tw_scan_dev<256>(histC + (size_t)b * 256, KpB, binC, KpC);
    const float T = __uint_as_float((binA << 20) | (binB << 8) | binC);
    unsigned nb = ccount[b]; if (nb > (unsigned)cap) nb = (unsigned)cap;
    const float alpha = *alphap;
    const unsigned stride = gridDim.x * 256;
    for (unsigned idx = blockIdx.x * 256 + threadIdx.x; idx < nb; idx += stride) {
        const float v = cand_val[(size_t)b * cap + idx];
        if (v < T) continue;
        const unsigned pij = cand_idx[(size_t)b * cap + idx];
        const unsigned i = pij >> 12, j = pij & 4095u;
        float4 dj = jdata[b * N + j];
        atomicAdd(&out[(size_t)(b * N + i) * 2 + 0], alpha * v * dj.z);
        atomicAdd(&out[(size_t)(b * N + i) * 2 + 1], alpha * v * dj.w);
        if ((pij >> 18) != ((pij >> 6) & 63u)) {   // off-diagonal tile -> mirror
            float4 di = jdata[b * N + i];
            atomicAdd(&out[(size_t)(b * N + j) * 2 + 0], alpha * v * di.z);
            atomicAdd(&out[(size_t)(b * N + j) * 2 + 1], alpha * v * di.w);
        }
    }
}

// ---------------- legacy fallback (round-1 pipeline) ----------------

__global__ void tw_precompute(const float* __restrict__ zr, const float* __restrict__ zi,
                              float4* __restrict__ jdata, unsigned* __restrict__ state,
                              int total, int B, unsigned K) {
    int idx = blockIdx.x * blockDim.x + threadIdx.x;
    if (idx < total) {
        float r = zr[idx], m = zi[idx];
        float amp = sqrtf(r * r + m * m);
        float phi = atan2f(m, r);
        jdata[idx] = make_float4(amp, phi, r, m);
    }
    if (idx < B) { state[idx * 2 + 0] = 0u; state[idx * 2 + 1] = K; }
}

template <int PASS>
__global__ void tw_hist(const float4* __restrict__ jdata, unsigned* __restrict__ hist,
                        const unsigned* __restrict__ state,
                        const float* ksp, const float* kbp, const float* sensp, int N) {
    constexpr int NB = (PASS == 3) ? 256 : 4096;
    __shared__ float sa[256], sphi[256];
    __shared__ unsigned lh[NB];
    const int b = blockIdx.z;
    const int i = blockIdx.x * 256 + threadIdx.x;
    const int j0 = blockIdx.y * 256;

    for (int k = threadIdx.x; k < NB; k += 256) lh[k] = 0u;

    float4 mine = jdata[b * N + i];
    float amp_i = mine.x, phi_i = mine.y;
    float4 jd = jdata[b * N + j0 + threadIdx.x];
    sa[threadIdx.x] = jd.x; sphi[threadIdx.x] = jd.y;

    const float sens = *sensp;
    const float expo = tw_expo(ksp, kbp);
    unsigned pf = 0;
    if (PASS > 1) pf = state[b * 2 + 0];
    __syncthreads();

    for (int j = 0; j < 256; ++j) {
        float R = tw_R(amp_i, phi_i, sa[j], sphi[j], sens, expo);
        unsigned bits = __float_as_uint(R);
        if (PASS == 1) {
            atomicAdd(&lh[bits >> 20], 1u);
        } else if (PASS == 2) {
            if ((bits >> 20) == (pf >> 20)) atomicAdd(&lh[(bits >> 8) & 0xFFFu], 1u);
        } else {
            if ((bits >> 8) == (pf >> 8)) atomicAdd(&lh[bits & 0xFFu], 1u);
        }
    }
    __syncthreads();
    for (int k = threadIdx.x; k < NB; k += 256) {
        unsigned v = lh[k];
        if (v) atomicAdd(&hist[b * NB + k], v);
    }
}

template <int NB, int SHIFT>
__global__ void tw_scan(const unsigned* __restrict__ hist, unsigned* __restrict__ state,
                        float* __restrict__ thr, int B) {
    __shared__ unsigned ps[256];
    constexpr int CHUNK = NB / 256;
    const int t = threadIdx.x;
    for (int b = 0; b < B; ++b) {
        const unsigned* h = hist + b * NB;
        unsigned prefix = state[b * 2 + 0];
        unsigned Kp     = state[b * 2 + 1];
        unsigned s = 0;
        for (int k = 0; k < CHUNK; ++k) {
            int bin = NB - 1 - (t * CHUNK + k);
            s += h[bin];
        }
        ps[t] = s;
        __syncthreads();
        for (int off = 1; off < 256; off <<= 1) {
            unsigned v = (t >= off) ? ps[t - off] : 0u;
            __syncthreads();
            ps[t] += v;
            __syncthreads();
        }
        unsigned excl = (t == 0) ? 0u : ps[t - 1];
        unsigned incl = ps[t];
        if (excl < Kp && Kp <= incl) {
            unsigned run = excl;
            for (int k = 0; k < CHUNK; ++k) {
                int bin = NB - 1 - (t * CHUNK + k);
                unsigned c = h[bin];
                if (run + c >= Kp) {
                    unsigned npf = prefix | ((unsigned)bin << SHIFT);
                    state[b * 2 + 0] = npf;
                    state[b * 2 + 1] = Kp - run;
                    if (SHIFT == 0) thr[b] = __uint_as_float(npf);
                    break;
                }
                run += c;
            }
        }
        __syncthreads();
    }
}

__global__ void tw_matvec(const float4* __restrict__ jdata, const float* __restrict__ thr,
                          const float* alphap, const float* ksp, const float* kbp,
                          const float* sensp, float* __restrict__ out, int N) {
    const int b = blockIdx.y;
    const int wid = threadIdx.x >> 6;
    const int lane = threadIdx.x & 63;
    const int i = blockIdx.x * 4 + wid;

    float4 mine = jdata[b * N + i];
    float amp_i = mine.x, phi_i = mine.y;
    const float sens = *sensp;
    const float expo = tw_expo(ksp, kbp);
    const float T = thr[b];
    const float alpha = *alphap;

    float ar = 0.0f, ai = 0.0f;
    for (int j = lane; j < N; j += 64) {
        float4 jd = jdata[b * N + j];
        float R = tw_R(amp_i, phi_i, jd.x, jd.y, sens, expo);
        if (R >= T) { ar += R * jd.z; ai += R * jd.w; }
    }
    for (int off = 32; off; off >>= 1) {
        ar += __shfl_down(ar, off);
        ai += __shfl_down(ai, off);
    }
    if (lane == 0) {
        out[(b * N + i) * 2 + 0] = alpha * ar;
        out[(b * N + i) * 2 + 1] = alpha * ai;
    }
}

// ---------------- launch ----------------

static inline size_t tw_align(size_t x) { return (x + 255) & ~(size_t)255; }

extern "C" void kernel_launch(void* const* d_in, const int* in_sizes, int n_in,
                              void* d_out, int out_size, void* d_ws, size_t ws_size,
                              hipStream_t stream) {
    const float* zr    = (const float*)d_in[0];
    const float* zi    = (const float*)d_in[1];
    const float* alpha = (const float*)d_in[2];
    const float* ks    = (const float*)d_in[3];
    const float* kb    = (const float*)d_in[4];
    const float* sens  = (const float*)d_in[5];
    float* out = (float*)d_out;

    const int N = TW_N;
    const int B = in_sizes[0] / N;
    const int total = B * N;

    long long tot2 = (long long)N * N;
    long long kv = (long long)8 * N;
    if (kv < 1) kv = 1;
    if (kv > tot2 - 1) kv = tot2 - 1;
    const unsigned K = (unsigned)(kv + 1);  // rank of threshold value (1-based)

    char* ws = (char*)d_ws;

    // ---- Round-13 persistent layout ----
    size_t p_hP   = 0;                                              // NPART*B*2048
    size_t p_h16c = p_hP + (size_t)TW_NPART * B * 2048 * sizeof(unsigned);
    size_t p_h16  = p_h16c + (size_t)B * 256 * sizeof(unsigned);
    size_t p_hLoc = p_h16 + (size_t)B * 65536 * sizeof(unsigned);
    size_t p_hLo  = p_hLoc + (size_t)B * 256 * sizeof(unsigned);
    size_t p_bar  = p_hLo + (size_t)B * 65536 * sizeof(unsigned);
    size_t p_zend = p_bar + (size_t)B * 2 * sizeof(unsigned);
    size_t p_seg  = tw_align(p_zend);
    size_t p_end  = p_seg + (size_t)B * TW_TBLK * TW_SEGCAP * sizeof(uint2);

    static int persist_max = -1;
    if (persist_max < 0) {
        int perCU = 0, nCU = 0, dev = 0;
        (void)hipGetDevice(&dev);
        if (hipOccupancyMaxActiveBlocksPerMultiprocessor(
                &perCU, (const void*)tw_p3, 256, 0) != hipSuccess) perCU = 0;
        if (hipDeviceGetAttribute(&nCU, hipDeviceAttributeMultiprocessorCount,
                                  dev) != hipSuccess) nCU = 0;
        persist_max = perCU * nCU;
    }
    if (ws_size >= p_end && persist_max >= TW_TBLK * B) {
        unsigned* hP   = (unsigned*)(ws + p_hP);
        unsigned* h16c = (unsigned*)(ws + p_h16c);
        unsigned* h16  = (unsigned*)(ws + p_h16);
        unsigned* hLoc = (unsigned*)(ws + p_hLoc);
        unsigned* hLo  = (unsigned*)(ws + p_hLo);
        unsigned* bar  = (unsigned*)(ws + p_bar);
        uint2*    seg  = (uint2*)(ws + p_seg);
        (void)hipMemsetAsync(ws, 0, p_zend, stream);
        tw_p3<<<dim3(TW_TBLK, B), 256, 0, stream>>>(
            zr, zi, alpha, ks, kb, sens, out, out_size,
            hP, h16c, h16, hLoc, hLo, bar, seg, N, B, K);
        return;
    }

    // ---- Round-10 7-kernel fallback ----
    // layout: [hP(8 partials)|hA|hB|hC|cnt|ccount <- zeroed | jfast | jexact | cidx | cval | seg]
    size_t o_hP     = 0;
    size_t o_hA     = o_hP + (size_t)TW_NPART * B * 2048 * sizeof(unsigned);
    size_t o_hB     = o_hA + (size_t)B * 4096 * sizeof(unsigned);
    size_t o_hC     = o_hB + (size_t)B * 4096 * sizeof(unsigned);
    size_t o_cnt    = o_hC + (size_t)B * 256 * sizeof(unsigned);
    size_t o_ccount = o_cnt + (size_t)B * TW_TBLK * sizeof(unsigned);
    size_t o_zero_end = o_ccount + (size_t)B * sizeof(unsigned);
    size_t o_jfast  = tw_align(o_zero_end);
    size_t o_jexact = tw_align(o_jfast + (size_t)B * N * sizeof(float2));
    size_t o_cidx   = tw_align(o_jexact + (size_t)B * N * sizeof(float4));
    size_t o_cval   = tw_align(o_cidx + (size_t)B * TW_CAND_CAP * sizeof(unsigned));
    size_t o_seg    = tw_align(o_cval + (size_t)B * TW_CAND_CAP * sizeof(float));
    size_t o_end    = o_seg + (size_t)B * TW_TBLK * TW_SEGCAP * sizeof(unsigned);

    if (ws_size >= o_end) {
        unsigned* hP     = (unsigned*)(ws + o_hP);
        unsigned* hA     = (unsigned*)(ws + o_hA);
        unsigned* hB     = (unsigned*)(ws + o_hB);
        unsigned* hC     = (unsigned*)(ws + o_hC);
        unsigned* cnt    = (unsigned*)(ws + o_cnt);
        unsigned* ccount = (unsigned*)(ws + o_ccount);
        float2*   jfast  = (float2*)(ws + o_jfast);
        float4*   jexact = (float4*)(ws + o_jexact);
        unsigned* cidx   = (unsigned*)(ws + o_cidx);
        float*    cval   = (float*)(ws + o_cval);
        unsigned* seg    = (unsigned*)(ws + o_seg);

        const int zero_words = (int)(o_zero_end / sizeof(unsigned));
        tw_init<<<128, 256, 0, stream>>>(zr, zi, jfast, jexact, (unsigned*)ws, zero_words,
                                         out, out_size, ks, kb, total);

        dim3 tgrid(TW_TBLK, B);
        tw_histW<<<tgrid, 256, 0, stream>>>(jfast, hP, sens, N, B);
        tw_collectW<<<tgrid, 256, 0, stream>>>(jfast, hP, seg, cnt, sens, N, B, K);
        tw_gexact<<<tgrid, 256, 0, stream>>>(seg, cnt, cidx, cval, jexact, hA, ccount,
                                             ks, kb, sens, N, TW_TBLK, TW_CAND_CAP);
        tw_chist1f<<<dim3(TW_CBLK, B), 256, 0, stream>>>(cval, cidx, ccount, hA, hB, K, TW_CAND_CAP);
        tw_chist2f<<<dim3(TW_CBLK, B), 256, 0, stream>>>(cval, cidx, ccount, hA, hB, hC, K, TW_CAND_CAP);
        tw_scatterf<<<dim3(TW_SBLK, B), 256, 0, stream>>>(cval, cidx, ccount, hA, hB, hC,
                                                          jexact, alpha, out, K, N, TW_CAND_CAP);
        return;
    }

    // ---- legacy fallback (round-1 pipeline) ----
    size_t l_jdata = 0;
    size_t l_h1 = l_jdata + (size_t)B * N * sizeof(float4);
    size_t l_h2 = l_h1 + (size_t)B * 4096 * sizeof(unsigned);
    size_t l_h3 = l_h2 + (size_t)B * 4096 * sizeof(unsigned);
    size_t l_state = l_h3 + (size_t)B * 256 * sizeof(unsigned);
    size_t l_thr = l_state + (size_t)B * 2 * sizeof(unsigned);
    size_t l_end = l_thr + (size_t)B * sizeof(float);

    float4* jdata = (float4*)(ws + l_jdata);
    unsigned* h1 = (unsigned*)(ws + l_h1);
    unsigned* h2 = (unsigned*)(ws + l_h2);
    unsigned* h3 = (unsigned*)(ws + l_h3);
    unsigned* state = (unsigned*)(ws + l_state);
    float* thr = (float*)(ws + l_thr);

    (void)hipMemsetAsync(ws + l_h1, 0, l_end - l_h1, stream);

    tw_precompute<<<(total + 255) / 256, 256, 0, stream>>>(zr, zi, jdata, state, total, B, K);

    dim3 hgrid(N / 256, N / 256, B);
    tw_hist<1><<<hgrid, 256, 0, stream>>>(jdata, h1, state, ks, kb, sens, N);
    tw_scan<4096, 20><<<1, 256, 0, stream>>>(h1, state, thr, B);
    tw_hist<2><<<hgrid, 256, 0, stream>>>(jdata, h2, state, ks, kb, sens, N);
    tw_scan<4096, 8><<<1, 256, 0, stream>>>(h2, state, thr, B);
    tw_hist<3><<<hgrid, 256, 0, stream>>>(jdata, h3, state, ks, kb, sens, N);
    tw_scan<256, 0><<<1, 256, 0, stream>>>(h3, state, thr, B);

    tw_matvec<<<dim3(N / 4, B), 256, 0, stream>>>(jdata, thr, alpha, ks, kb, sens, out, N);
}